// Round 10
// baseline (525.006 us; speedup 1.0000x reference)
//
#include <hip/hip_runtime.h>
#include <cstddef>

constexpr int NODES = 100000;
constexpr int NPB   = 32;                      // nodes per bucket
constexpr int NBUCK = (NODES + NPB - 1) / NPB; // 3125 (×32 = exactly 100000)
constexpr int NREP  = 8;                       // cursor replicas (XCD-aligned)
constexpr int NFLAT = NBUCK * NREP;            // 25000
constexpr int CAP   = 2048;                    // max rows per bucket

typedef unsigned int uint;
typedef unsigned short ushort_t;
typedef __attribute__((ext_vector_type(8)))  _Float16 f16x8;
typedef __attribute__((ext_vector_type(16))) float    f32x16;
typedef __attribute__((ext_vector_type(4)))  float    f32x4;
typedef __attribute__((ext_vector_type(4)))  uint     u32x4;

__device__ __forceinline__ int rfl_i(int x) {
    return __builtin_amdgcn_readfirstlane(x);
}
__device__ __forceinline__ float rfl_f(float x) {
    return __int_as_float(__builtin_amdgcn_readfirstlane(__float_as_int(x)));
}
__device__ __forceinline__ uint pkh2(float a, float b) {
    union { uint u; _Float16 h[2]; } p;
    p.h[0] = (_Float16)a; p.h[1] = (_Float16)b;
    return p.u;
}

// ---- pass 1: padded replicated bucket histogram (nt streaming reads) ----
// edge->(wave,rep) mapping MUST match scatter_rows exactly.
__global__ __launch_bounds__(256) void count_pad(
    const int* __restrict__ idx, int* __restrict__ cntp, int E)
{
    const int rep = blockIdx.x & (NREP - 1);
    const int l = threadIdx.x & 63;
    const int g = l >> 1, q = l & 1;
    int wid = (blockIdx.x * blockDim.x + threadIdx.x) >> 6;
    int nw  = (gridDim.x * blockDim.x) >> 6;
    for (int base = wid * 32; base < E; base += nw * 32) {
        int e = base + g;
        if (e < E && q == 0) {
            int n = __builtin_nontemporal_load(idx + e);
            atomicAdd(&cntp[(size_t)((n >> 5) * NREP + rep) * 32], 1);
        }
    }
}

// ---- pass 2: single-block scan over PADDED counters -> flat starts + padded cursors ----
__global__ __launch_bounds__(1024) void scan_pad(
    const int* __restrict__ cntp, int* __restrict__ sflat, int* __restrict__ cursp)
{
    __shared__ int wsum[16];
    __shared__ int running_s;
    int tid = threadIdx.x, lane = tid & 63, wv = tid >> 6;
    if (tid == 0) running_s = 0;
    __syncthreads();
    for (int base = 0; base < NFLAT; base += 4096) {
        int i0 = base + tid * 4;
        int c0 = 0, c1 = 0, c2 = 0, c3 = 0;
        if (i0     < NFLAT) c0 = cntp[(size_t)(i0    ) * 32];
        if (i0 + 1 < NFLAT) c1 = cntp[(size_t)(i0 + 1) * 32];
        if (i0 + 2 < NFLAT) c2 = cntp[(size_t)(i0 + 2) * 32];
        if (i0 + 3 < NFLAT) c3 = cntp[(size_t)(i0 + 3) * 32];
        int t = c0 + c1 + c2 + c3;
        int x = t;
        #pragma unroll
        for (int d = 1; d < 64; d <<= 1) {
            int v = __shfl_up(x, d);
            if (lane >= d) x += v;
        }
        if (lane == 63) wsum[wv] = x;
        __syncthreads();
        if (wv == 0 && lane < 16) {
            int y = wsum[lane];
            #pragma unroll
            for (int d = 1; d < 16; d <<= 1) {
                int v = __shfl_up(y, d);
                if (lane >= d) y += v;
            }
            wsum[lane] = y;
        }
        __syncthreads();
        int woff = (wv > 0) ? wsum[wv - 1] : 0;
        int r = running_s;
        int excl = r + woff + (x - t);
        int s0 = excl, s1 = excl + c0, s2 = s1 + c1, s3 = s2 + c2;
        if (i0     < NFLAT) { sflat[i0]     = s0; cursp[(size_t)(i0    ) * 32] = s0; }
        if (i0 + 1 < NFLAT) { sflat[i0 + 1] = s1; cursp[(size_t)(i0 + 1) * 32] = s1; }
        if (i0 + 2 < NFLAT) { sflat[i0 + 2] = s2; cursp[(size_t)(i0 + 2) * 32] = s2; }
        if (i0 + 3 < NFLAT) { sflat[i0 + 3] = s3; cursp[(size_t)(i0 + 3) * 32] = s3; }
        int total = wsum[15];
        __syncthreads();
        if (tid == 0) running_s = r + total;
    }
    __syncthreads();
    if (tid == 0) sflat[NFLAT] = running_s;
}

// ---- pass 3: scatter f16 premultiplied rows into bucket-replica regions ----
// 2 lanes per edge (16B halves); wtag = w with 5 mantissa LSBs = nloc.
// All input reads non-temporal: keep append tails resident in L2/L3.
__global__ __launch_bounds__(256) void scatter_rows(
    const f32x4* __restrict__ cf4, const float* __restrict__ wts,
    const int* __restrict__ idx, int* __restrict__ cursp,
    uint* __restrict__ wtag, u32x4* __restrict__ rows, int E)
{
    const int rep = blockIdx.x & (NREP - 1);
    const int l = threadIdx.x & 63;
    const int g = l >> 1, q = l & 1;
    int wid = (blockIdx.x * blockDim.x + threadIdx.x) >> 6;
    int nw  = (gridDim.x * blockDim.x) >> 6;
    for (int base = wid * 32; base < E; base += nw * 32) {
        int e = base + g;
        bool valid = e < E;
        f32x4 c0 = {0.f, 0.f, 0.f, 0.f}, c1 = {0.f, 0.f, 0.f, 0.f};
        float w = 0.f;
        int slot = 0;
        if (valid) {
            c0 = __builtin_nontemporal_load(cf4 + (size_t)e * 4 + q * 2);
            c1 = __builtin_nontemporal_load(cf4 + (size_t)e * 4 + q * 2 + 1);
            w  = __builtin_nontemporal_load(wts + e);
            if (q == 0) {
                int n = __builtin_nontemporal_load(idx + e);
                slot = atomicAdd(&cursp[(size_t)((n >> 5) * NREP + rep) * 32], 1);
                wtag[slot] = (__float_as_uint(w) & ~31u) | (uint)(n & 31);
            }
        }
        slot = __shfl(slot, l & ~1);
        if (valid) {
            u32x4 o;
            o.x = pkh2(c0.x * w, c0.y * w);
            o.y = pkh2(c0.z * w, c0.w * w);
            o.z = pkh2(c1.x * w, c1.y * w);
            o.w = pkh2(c1.z * w, c1.w * w);
            rows[(size_t)slot * 2 + q] = o;
        }
    }
}

// ---- pass 4: per-bucket in-place node sort, REGISTER staging (12.7 KB LDS) ----
__global__ __launch_bounds__(256) void bucket_sort(
    const int* __restrict__ sflat, const uint* __restrict__ wtag,
    u32x4* __restrict__ rows, int* __restrict__ starts_n,
    float* __restrict__ den, int* __restrict__ flag)
{
    __shared__ uint     lwtag[CAP];        // 8 KB
    __shared__ ushort_t ldst[CAP];         // 4 KB
    __shared__ int   hist[NPB], lcur[NPB];
    __shared__ float lden[NPB];

    const int tid = threadIdx.x;
    const int b = blockIdx.x;
    const int rs = sflat[b * NREP];
    const int re = sflat[b * NREP + NREP];
    const int n = re - rs;

    if (tid < NPB) { hist[tid] = 0; lden[tid] = 0.f; }
    __syncthreads();
    if (n > CAP) { if (tid == 0) *flag = 1; return; }

    // A: tag load + per-node histogram + den
    for (int i = tid; i < n; i += 256) {
        uint t = __builtin_nontemporal_load(wtag + rs + i);
        lwtag[i] = t;
        atomicAdd(&hist[(int)(t & 31u)], 1);
        atomicAdd(&lden[(int)(t & 31u)], __uint_as_float(t & ~31u));
    }
    __syncthreads();

    // B: 32-lane scan -> local starts; emit global starts_n, den
    if (tid < NPB) {
        int c = hist[tid];
        int x = c;
        #pragma unroll
        for (int d = 1; d < NPB; d <<= 1) {
            int v = __shfl_up(x, d);
            if (tid >= d) x += v;
        }
        lcur[tid] = x - c;
        starts_n[b * NPB + tid] = rs + x - c;
        den[b * NPB + tid] = lden[tid];
        if (b == NBUCK - 1 && tid == 0) starts_n[NODES] = re;
    }
    __syncthreads();

    // C: rank each row within its node (order arbitrary; sum commutative)
    for (int i = tid; i < n; i += 256) {
        int d = atomicAdd(&lcur[(int)(lwtag[i] & 31u)], 1);
        ldst[i] = (ushort_t)d;
    }
    __syncthreads();

    // D: permute rows through registers (8 rows/thread, static unroll).
    // __syncthreads' implicit fences order the reads before the writes.
    u32x4 ra[8], rb[8];
    int   dk[8];
    #pragma unroll
    for (int k = 0; k < 8; ++k) {
        int i = tid + k * 256;
        dk[k] = -1;
        if (i < n) {
            ra[k] = rows[(size_t)(rs + i) * 2];
            rb[k] = rows[(size_t)(rs + i) * 2 + 1];
            dk[k] = (int)ldst[i];
        }
    }
    __syncthreads();
    #pragma unroll
    for (int k = 0; k < 8; ++k) {
        if (dk[k] >= 0) {
            rows[(size_t)(rs + dk[k]) * 2]     = ra[k];
            rows[(size_t)(rs + dk[k]) * 2 + 1] = rb[k];
        }
    }
}

// ---- pass 5: per-node segment gather, MFMA, register reduce ----
__global__ __launch_bounds__(256) void gather_seg(
    const float* __restrict__ emb, const u32x4* __restrict__ rows,
    const int* __restrict__ starts, const float* __restrict__ den,
    float* __restrict__ out, const int* __restrict__ flag)
{
    if (*flag) return;
    const int l    = threadIdx.x & 63;
    const int ucol = l & 31;
    const int h    = l >> 5;

    f16x8 b0, b1;
    #pragma unroll
    for (int j = 0; j < 8; ++j) {
        b0[j] = (_Float16)emb[ucol * 16 + 8 * h + j];
        b1[j] = (_Float16)emb[(ucol + 32) * 16 + 8 * h + j];
    }

    f32x16 zacc;
    #pragma unroll
    for (int i = 0; i < 16; ++i) zacc[i] = 0.f;

    int gw = (blockIdx.x * blockDim.x + threadIdx.x) >> 6;
    int nw = (gridDim.x * blockDim.x) >> 6;

    for (int node = gw; node < NODES; node += nw) {
        int s = rfl_i(starts[node]);
        int e = rfl_i(starts[node + 1]);
        int cnt = e - s;
        float r0 = 0.f, r1 = 0.f;
        for (int ch = 0; ch < cnt; ch += 32) {
            int row = s + ch + ucol;
            bool valid = (ch + ucol) < cnt;
            u32x4 v = __builtin_nontemporal_load(rows + (size_t)row * 2 + h);
            if (!valid) { v.x = 0; v.y = 0; v.z = 0; v.w = 0; }
            f16x8 a;
            {
                union { u32x4 u; f16x8 f; } cvt;
                cvt.u = v;
                a = cvt.f;
            }
            f32x16 d0 = __builtin_amdgcn_mfma_f32_32x32x16_f16(a, b0, zacc, 0, 0, 0);
            f32x16 d1 = __builtin_amdgcn_mfma_f32_32x32x16_f16(a, b1, zacc, 0, 0, 0);
            float t0 = 0.f, t1 = 0.f;
            #pragma unroll
            for (int r = 0; r < 16; ++r) {
                t0 += fmaxf(d0[r], 0.f);
                t1 += fmaxf(d1[r], 0.f);
            }
            r0 += t0; r1 += t1;
        }
        r0 += __shfl_xor(r0, 32);
        r1 += __shfl_xor(r1, 32);
        float d = rfl_f(den[node]);
        out[(size_t)node * 64 + l] = (h ? r1 : r0) / d;
    }
}

// ================= guarded fallbacks (no-op when flag==0 / null) =================

__global__ __launch_bounds__(256) void zero_fb(
    float* __restrict__ out, float* __restrict__ den, int nout,
    const int* __restrict__ flag)
{
    if (flag && !*flag) return;
    int i = blockIdx.x * blockDim.x + threadIdx.x;
    int stride = gridDim.x * blockDim.x;
    for (int j = i; j < nout; j += stride) out[j] = 0.f;
    for (int j = i; j < NODES; j += stride) den[j] = 0.f;
}

__global__ __launch_bounds__(256) void edge_scatter_fb(
    const float* __restrict__ emb, const float* __restrict__ cf,
    const float* __restrict__ wts, const int* __restrict__ idx,
    float* __restrict__ num, float* __restrict__ den, int E,
    const int* __restrict__ flag)
{
    if (flag && !*flag) return;
    const int lane = threadIdx.x & 63;
    float er[16];
    #pragma unroll
    for (int f = 0; f < 16; ++f) er[f] = emb[lane * 16 + f];
    int wid = rfl_i((int)((blockIdx.x * blockDim.x + threadIdx.x) >> 6));
    int nw = (gridDim.x * blockDim.x) >> 6;
    for (int e = wid; e < E; e += nw) {
        const float* c = cf + (size_t)e * 16;
        float a = 0.f;
        #pragma unroll
        for (int f = 0; f < 16; ++f) a = fmaf(c[f], er[f], a);
        float wv = wts[e];
        int n = idx[e];
        unsafeAtomicAdd(num + (size_t)n * 64 + lane, fmaxf(a, 0.f) * wv);
        if (lane == 0) unsafeAtomicAdd(den + n, wv);
    }
}

__global__ __launch_bounds__(256) void divide_fb(
    float* __restrict__ out, const float* __restrict__ den, int nvec,
    const int* __restrict__ flag)
{
    if (flag && !*flag) return;
    int i = blockIdx.x * blockDim.x + threadIdx.x;
    int stride = gridDim.x * blockDim.x;
    float4* o4 = reinterpret_cast<float4*>(out);
    for (; i < nvec; i += stride) {
        float4 v = o4[i];
        float d = den[i >> 4];
        v.x /= d; v.y /= d; v.z /= d; v.w /= d;
        o4[i] = v;
    }
}

extern "C" void kernel_launch(void* const* d_in, const int* in_sizes, int n_in,
                              void* d_out, int out_size, void* d_ws, size_t ws_size,
                              hipStream_t stream)
{
    const float* emb = (const float*)d_in[0];   // (64,16)
    const float* cf  = (const float*)d_in[1];   // (E,16)
    const float* wts = (const float*)d_in[2];   // (E,)
    const int*   idx = (const int*)d_in[3];     // (E,)
    int E = in_sizes[2];
    float* out = (float*)d_out;

    // ws layout
    char* p = (char*)d_ws;
    auto take = [&](size_t bytes) { char* r = p; p += (bytes + 255) & ~(size_t)255; return r; };
    int*  cntp     = (int*)take((size_t)NFLAT * 32 * sizeof(int));   // 3.2 MB padded
    int*  cursp    = (int*)take((size_t)NFLAT * 32 * sizeof(int));   // 3.2 MB padded
    int*  sflat    = (int*)take((size_t)(NFLAT + 1) * sizeof(int));
    int*  starts_n = (int*)take((size_t)(NODES + 1) * sizeof(int));
    float* den     = (float*)take((size_t)NODES * sizeof(float));
    int*  flag     = (int*)take(256);
    uint* wtag     = (uint*)take((size_t)E * sizeof(uint));
    u32x4* rows    = (u32x4*)take(((size_t)E + 40) * 2 * sizeof(u32x4)); // f16 rows + slack
    size_t need = (size_t)(p - (char*)d_ws);

    if (ws_size >= need) {
        (void)hipMemsetAsync(cntp, 0, (size_t)NFLAT * 32 * sizeof(int), stream);
        (void)hipMemsetAsync(flag, 0, sizeof(int), stream);
        count_pad<<<4096, 256, 0, stream>>>(idx, cntp, E);
        scan_pad<<<1, 1024, 0, stream>>>(cntp, sflat, cursp);
        scatter_rows<<<4096, 256, 0, stream>>>(
            (const f32x4*)cf, wts, idx, cursp, wtag, rows, E);
        bucket_sort<<<NBUCK, 256, 0, stream>>>(sflat, wtag, rows, starts_n, den, flag);
        gather_seg<<<2048, 256, 0, stream>>>(emb, rows, starts_n, den, out, flag);
        // guarded fallback chain (no-ops when flag==0)
        zero_fb<<<2048, 256, 0, stream>>>(out, den, out_size, flag);
        edge_scatter_fb<<<4096, 256, 0, stream>>>(emb, cf, wts, idx, out, den, E, flag);
        divide_fb<<<2048, 256, 0, stream>>>(out, den, out_size / 4, flag);
    } else {
        // host fallback: plain atomic scatter (needs only NODES floats of ws)
        float* den2 = (float*)d_ws;
        (void)hipMemsetAsync(d_out, 0, (size_t)out_size * sizeof(float), stream);
        (void)hipMemsetAsync(d_ws, 0, (size_t)NODES * sizeof(float), stream);
        edge_scatter_fb<<<4096, 256, 0, stream>>>(emb, cf, wts, idx, out, den2, E, nullptr);
        divide_fb<<<2048, 256, 0, stream>>>(out, den2, out_size / 4, nullptr);
    }
}

// Round 11
// 437.510 us; speedup vs baseline: 1.2000x; 1.2000x over previous
//
#include <hip/hip_runtime.h>
#include <cstddef>

constexpr int NODES = 100000;
constexpr int NPB   = 32;                      // nodes per bucket
constexpr int NBUCK = (NODES + NPB - 1) / NPB; // 3125 (×32 = exactly 100000)
constexpr int NREP  = 8;                       // cursor replicas (XCD-aligned)
constexpr int NFLAT = NBUCK * NREP;            // 25000
constexpr int CAP   = 1280;                    // max rows per bucket (mean 1024, 8 sigma)

typedef unsigned int uint;
typedef __attribute__((ext_vector_type(8)))  _Float16 f16x8;
typedef __attribute__((ext_vector_type(16))) float    f32x16;
typedef __attribute__((ext_vector_type(4)))  float    f32x4;
typedef __attribute__((ext_vector_type(4)))  uint     u32x4;

__device__ __forceinline__ int rfl_i(int x) {
    return __builtin_amdgcn_readfirstlane(x);
}
__device__ __forceinline__ uint pkh2(float a, float b) {
    union { uint u; _Float16 h[2]; } p;
    p.h[0] = (_Float16)a; p.h[1] = (_Float16)b;
    return p.u;
}

// ---- pass 1: padded replicated bucket histogram ----
// edge->(wave,rep) mapping MUST match scatter_rows exactly.
__global__ __launch_bounds__(256) void count_pad(
    const int* __restrict__ idx, int* __restrict__ cntp, int E)
{
    const int rep = blockIdx.x & (NREP - 1);
    const int l = threadIdx.x & 63;
    const int g = l >> 1, q = l & 1;
    int wid = (blockIdx.x * blockDim.x + threadIdx.x) >> 6;
    int nw  = (gridDim.x * blockDim.x) >> 6;
    for (int base = wid * 32; base < E; base += nw * 32) {
        int e = base + g;
        if (e < E && q == 0) {
            int n = __builtin_nontemporal_load(idx + e);
            atomicAdd(&cntp[(size_t)((n >> 5) * NREP + rep) * 32], 1);
        }
    }
}

// ---- pass 2: single-block scan over PADDED counters -> flat starts + padded cursors ----
__global__ __launch_bounds__(1024) void scan_pad(
    const int* __restrict__ cntp, int* __restrict__ sflat, int* __restrict__ cursp)
{
    __shared__ int wsum[16];
    __shared__ int running_s;
    int tid = threadIdx.x, lane = tid & 63, wv = tid >> 6;
    if (tid == 0) running_s = 0;
    __syncthreads();
    for (int base = 0; base < NFLAT; base += 4096) {
        int i0 = base + tid * 4;
        int c0 = 0, c1 = 0, c2 = 0, c3 = 0;
        if (i0     < NFLAT) c0 = cntp[(size_t)(i0    ) * 32];
        if (i0 + 1 < NFLAT) c1 = cntp[(size_t)(i0 + 1) * 32];
        if (i0 + 2 < NFLAT) c2 = cntp[(size_t)(i0 + 2) * 32];
        if (i0 + 3 < NFLAT) c3 = cntp[(size_t)(i0 + 3) * 32];
        int t = c0 + c1 + c2 + c3;
        int x = t;
        #pragma unroll
        for (int d = 1; d < 64; d <<= 1) {
            int v = __shfl_up(x, d);
            if (lane >= d) x += v;
        }
        if (lane == 63) wsum[wv] = x;
        __syncthreads();
        if (wv == 0 && lane < 16) {
            int y = wsum[lane];
            #pragma unroll
            for (int d = 1; d < 16; d <<= 1) {
                int v = __shfl_up(y, d);
                if (lane >= d) y += v;
            }
            wsum[lane] = y;
        }
        __syncthreads();
        int woff = (wv > 0) ? wsum[wv - 1] : 0;
        int r = running_s;
        int excl = r + woff + (x - t);
        int s0 = excl, s1 = excl + c0, s2 = s1 + c1, s3 = s2 + c2;
        if (i0     < NFLAT) { sflat[i0]     = s0; cursp[(size_t)(i0    ) * 32] = s0; }
        if (i0 + 1 < NFLAT) { sflat[i0 + 1] = s1; cursp[(size_t)(i0 + 1) * 32] = s1; }
        if (i0 + 2 < NFLAT) { sflat[i0 + 2] = s2; cursp[(size_t)(i0 + 2) * 32] = s2; }
        if (i0 + 3 < NFLAT) { sflat[i0 + 3] = s3; cursp[(size_t)(i0 + 3) * 32] = s3; }
        int total = wsum[15];
        __syncthreads();
        if (tid == 0) running_s = r + total;
    }
    __syncthreads();
    if (tid == 0) sflat[NFLAT] = running_s;
}

// ---- pass 3: scatter f16 premultiplied rows into bucket-replica regions ----
// 2 lanes per edge (16B halves); wtag = w with 5 mantissa LSBs = nloc.
__global__ __launch_bounds__(256) void scatter_rows(
    const f32x4* __restrict__ cf4, const float* __restrict__ wts,
    const int* __restrict__ idx, int* __restrict__ cursp,
    uint* __restrict__ wtag, u32x4* __restrict__ rows, int E)
{
    const int rep = blockIdx.x & (NREP - 1);
    const int l = threadIdx.x & 63;
    const int g = l >> 1, q = l & 1;
    int wid = (blockIdx.x * blockDim.x + threadIdx.x) >> 6;
    int nw  = (gridDim.x * blockDim.x) >> 6;
    for (int base = wid * 32; base < E; base += nw * 32) {
        int e = base + g;
        bool valid = e < E;
        f32x4 c0 = {0.f, 0.f, 0.f, 0.f}, c1 = {0.f, 0.f, 0.f, 0.f};
        float w = 0.f;
        int slot = 0;
        if (valid) {
            c0 = __builtin_nontemporal_load(cf4 + (size_t)e * 4 + q * 2);
            c1 = __builtin_nontemporal_load(cf4 + (size_t)e * 4 + q * 2 + 1);
            w  = __builtin_nontemporal_load(wts + e);
            if (q == 0) {
                int n = __builtin_nontemporal_load(idx + e);
                slot = atomicAdd(&cursp[(size_t)((n >> 5) * NREP + rep) * 32], 1);
                wtag[slot] = (__float_as_uint(w) & ~31u) | (uint)(n & 31);
            }
        }
        slot = __shfl(slot, l & ~1);
        if (valid) {
            u32x4 o;
            o.x = pkh2(c0.x * w, c0.y * w);
            o.y = pkh2(c0.z * w, c0.w * w);
            o.z = pkh2(c1.x * w, c1.y * w);
            o.w = pkh2(c1.z * w, c1.w * w);
            rows[(size_t)slot * 2 + q] = o;
        }
    }
}

// ---- pass 4 (FUSED sort+gather): one block per bucket ----
// A: histogram+den from wtag; B: 32-lane scan; C: rank + global->LDS sorted copy;
// D: per-wave node processing: ds_read_b128 chunks, 2x MFMA, register relu-reduce.
// MFMA 32x32x16 f16 mappings (verified R5-R10):
//   A-frag: lane(ucol,h) supplies A[row=ucol][k=8h+j]
//   B-frag: lane supplies B[k=8h+j][n=ucol] (emb^T)
//   D: col=lane&31, row=(reg&3)+8*(reg>>2)+4*(lane>>5)
__global__ __launch_bounds__(256) void sort_gather(
    const float* __restrict__ emb, const int* __restrict__ sflat,
    const uint* __restrict__ wtag, const u32x4* __restrict__ rows,
    float* __restrict__ out, int* __restrict__ flag)
{
    __shared__ u32x4 lrows[CAP * 2];      // 40 KB sorted rows
    __shared__ uint  lwtag[CAP];          // 5 KB
    __shared__ int   hist[NPB], lcur[NPB], lstart[NPB];
    __shared__ float lden[NPB];

    const int tid  = threadIdx.x;
    const int l    = tid & 63;
    const int wv   = tid >> 6;
    const int ucol = l & 31;
    const int h    = l >> 5;
    const int b    = blockIdx.x;

    const int rs = sflat[b * NREP];
    const int re = sflat[b * NREP + NREP];
    const int n  = re - rs;

    if (tid < NPB) { hist[tid] = 0; lden[tid] = 0.f; }
    __syncthreads();
    if (n > CAP) { if (tid == 0) *flag = 1; return; }

    // A: tag load + per-node histogram + den
    for (int i = tid; i < n; i += 256) {
        uint t = __builtin_nontemporal_load(wtag + rs + i);
        lwtag[i] = t;
        atomicAdd(&hist[(int)(t & 31u)], 1);
        atomicAdd(&lden[(int)(t & 31u)], __uint_as_float(t & ~31u));
    }
    __syncthreads();

    // B: 32-lane exclusive scan
    if (tid < NPB) {
        int c = hist[tid];
        int x = c;
        #pragma unroll
        for (int d = 1; d < NPB; d <<= 1) {
            int v = __shfl_up(x, d);
            if (tid >= d) x += v;
        }
        lstart[tid] = x - c;
        lcur[tid]   = x - c;
    }
    __syncthreads();

    // C: rank + sorted copy global->LDS (coalesced global reads, random LDS writes)
    for (int i = tid; i < n; i += 256) {
        int r = atomicAdd(&lcur[(int)(lwtag[i] & 31u)], 1);
        u32x4 va = rows[(size_t)(rs + i) * 2];
        u32x4 vb = rows[(size_t)(rs + i) * 2 + 1];
        lrows[r * 2]     = va;
        lrows[r * 2 + 1] = vb;
    }
    __syncthreads();

    // D: each wave handles nodes wv, wv+4, ... (8 nodes/wave); no further syncs
    f16x8 b0, b1;
    #pragma unroll
    for (int j = 0; j < 8; ++j) {
        b0[j] = (_Float16)emb[ucol * 16 + 8 * h + j];
        b1[j] = (_Float16)emb[(ucol + 32) * 16 + 8 * h + j];
    }
    f32x16 zacc;
    #pragma unroll
    for (int i = 0; i < 16; ++i) zacc[i] = 0.f;

    for (int nl = wv; nl < NPB; nl += 4) {
        int s   = lstart[nl];
        int cnt = hist[nl];
        float r0 = 0.f, r1 = 0.f;
        for (int ch = 0; ch < cnt; ch += 32) {
            bool valid = (ch + ucol) < cnt;
            int pos = valid ? (s + ch + ucol) : 0;
            u32x4 v = lrows[pos * 2 + h];            // ds_read_b128
            if (!valid) { v.x = 0; v.y = 0; v.z = 0; v.w = 0; }
            f16x8 a;
            {
                union { u32x4 u; f16x8 f; } cvt;
                cvt.u = v;
                a = cvt.f;
            }
            f32x16 d0 = __builtin_amdgcn_mfma_f32_32x32x16_f16(a, b0, zacc, 0, 0, 0);
            f32x16 d1 = __builtin_amdgcn_mfma_f32_32x32x16_f16(a, b1, zacc, 0, 0, 0);
            float t0 = 0.f, t1 = 0.f;
            #pragma unroll
            for (int r = 0; r < 16; ++r) {
                t0 += fmaxf(d0[r], 0.f);
                t1 += fmaxf(d1[r], 0.f);
            }
            r0 += t0; r1 += t1;
        }
        r0 += __shfl_xor(r0, 32);
        r1 += __shfl_xor(r1, 32);
        int node = b * NPB + nl;
        float d = lden[nl];
        out[(size_t)node * 64 + l] = (h ? r1 : r0) / d;   // coalesced 256B
    }
}

// ================= guarded fallbacks (no-op when flag==0 / null) =================

__global__ __launch_bounds__(256) void zero_fb(
    float* __restrict__ out, float* __restrict__ den, int nout,
    const int* __restrict__ flag)
{
    if (flag && !*flag) return;
    int i = blockIdx.x * blockDim.x + threadIdx.x;
    int stride = gridDim.x * blockDim.x;
    for (int j = i; j < nout; j += stride) out[j] = 0.f;
    for (int j = i; j < NODES; j += stride) den[j] = 0.f;
}

__global__ __launch_bounds__(256) void edge_scatter_fb(
    const float* __restrict__ emb, const float* __restrict__ cf,
    const float* __restrict__ wts, const int* __restrict__ idx,
    float* __restrict__ num, float* __restrict__ den, int E,
    const int* __restrict__ flag)
{
    if (flag && !*flag) return;
    const int lane = threadIdx.x & 63;
    float er[16];
    #pragma unroll
    for (int f = 0; f < 16; ++f) er[f] = emb[lane * 16 + f];
    int wid = rfl_i((int)((blockIdx.x * blockDim.x + threadIdx.x) >> 6));
    int nw = (gridDim.x * blockDim.x) >> 6;
    for (int e = wid; e < E; e += nw) {
        const float* c = cf + (size_t)e * 16;
        float a = 0.f;
        #pragma unroll
        for (int f = 0; f < 16; ++f) a = fmaf(c[f], er[f], a);
        float wv = wts[e];
        int n = idx[e];
        unsafeAtomicAdd(num + (size_t)n * 64 + lane, fmaxf(a, 0.f) * wv);
        if (lane == 0) unsafeAtomicAdd(den + n, wv);
    }
}

__global__ __launch_bounds__(256) void divide_fb(
    float* __restrict__ out, const float* __restrict__ den, int nvec,
    const int* __restrict__ flag)
{
    if (flag && !*flag) return;
    int i = blockIdx.x * blockDim.x + threadIdx.x;
    int stride = gridDim.x * blockDim.x;
    float4* o4 = reinterpret_cast<float4*>(out);
    for (; i < nvec; i += stride) {
        float4 v = o4[i];
        float d = den[i >> 4];
        v.x /= d; v.y /= d; v.z /= d; v.w /= d;
        o4[i] = v;
    }
}

extern "C" void kernel_launch(void* const* d_in, const int* in_sizes, int n_in,
                              void* d_out, int out_size, void* d_ws, size_t ws_size,
                              hipStream_t stream)
{
    const float* emb = (const float*)d_in[0];   // (64,16)
    const float* cf  = (const float*)d_in[1];   // (E,16)
    const float* wts = (const float*)d_in[2];   // (E,)
    const int*   idx = (const int*)d_in[3];     // (E,)
    int E = in_sizes[2];
    float* out = (float*)d_out;

    // ws layout
    char* p = (char*)d_ws;
    auto take = [&](size_t bytes) { char* r = p; p += (bytes + 255) & ~(size_t)255; return r; };
    int*  cntp     = (int*)take((size_t)NFLAT * 32 * sizeof(int));   // 3.2 MB padded
    int*  cursp    = (int*)take((size_t)NFLAT * 32 * sizeof(int));   // 3.2 MB padded
    int*  sflat    = (int*)take((size_t)(NFLAT + 1) * sizeof(int));
    float* den     = (float*)take((size_t)NODES * sizeof(float));    // fallback only
    int*  flag     = (int*)take(256);
    uint* wtag     = (uint*)take((size_t)E * sizeof(uint));
    u32x4* rows    = (u32x4*)take(((size_t)E + 40) * 2 * sizeof(u32x4)); // f16 rows + slack
    size_t need = (size_t)(p - (char*)d_ws);

    if (ws_size >= need) {
        (void)hipMemsetAsync(cntp, 0, (size_t)NFLAT * 32 * sizeof(int), stream);
        (void)hipMemsetAsync(flag, 0, sizeof(int), stream);
        count_pad<<<4096, 256, 0, stream>>>(idx, cntp, E);
        scan_pad<<<1, 1024, 0, stream>>>(cntp, sflat, cursp);
        scatter_rows<<<4096, 256, 0, stream>>>(
            (const f32x4*)cf, wts, idx, cursp, wtag, rows, E);
        sort_gather<<<NBUCK, 256, 0, stream>>>(emb, sflat, wtag, rows, out, flag);
        // guarded fallback chain (no-ops when flag==0)
        zero_fb<<<2048, 256, 0, stream>>>(out, den, out_size, flag);
        edge_scatter_fb<<<4096, 256, 0, stream>>>(emb, cf, wts, idx, out, den, E, flag);
        divide_fb<<<2048, 256, 0, stream>>>(out, den, out_size / 4, flag);
    } else {
        // host fallback: plain atomic scatter (needs only NODES floats of ws)
        float* den2 = (float*)d_ws;
        (void)hipMemsetAsync(d_out, 0, (size_t)out_size * sizeof(float), stream);
        (void)hipMemsetAsync(d_ws, 0, (size_t)NODES * sizeof(float), stream);
        edge_scatter_fb<<<4096, 256, 0, stream>>>(emb, cf, wts, idx, out, den2, E, nullptr);
        divide_fb<<<2048, 256, 0, stream>>>(out, den2, out_size / 4, nullptr);
    }
}

// Round 12
// 423.013 us; speedup vs baseline: 1.2411x; 1.0343x over previous
//
#include <hip/hip_runtime.h>
#include <cstddef>

constexpr int NODES = 100000;
constexpr int NPB   = 32;                      // nodes per bucket
constexpr int NBUCK = (NODES + NPB - 1) / NPB; // 3125 (×32 = exactly 100000)
constexpr int NREP  = 8;                       // cursor replicas (XCD-aligned)
constexpr int NFLAT = NBUCK * NREP;            // 25000
constexpr int CAP   = 2048;                    // max records per bucket (mean 1024)

typedef unsigned int uint;
typedef unsigned long long u64;
typedef __attribute__((ext_vector_type(8)))  _Float16 f16x8;
typedef __attribute__((ext_vector_type(16))) float    f32x16;
typedef __attribute__((ext_vector_type(4)))  float    f32x4;

__device__ __forceinline__ int rfl_i(int x) {
    return __builtin_amdgcn_readfirstlane(x);
}

// ---- pass 1: padded replicated bucket histogram ----
// edge->rep mapping MUST match scatter_ew exactly (same grid, same loop).
__global__ __launch_bounds__(256) void count_pad(
    const int* __restrict__ idx, int* __restrict__ cntp, int E)
{
    const int rep = blockIdx.x & (NREP - 1);
    int i = blockIdx.x * blockDim.x + threadIdx.x;
    int stride = gridDim.x * blockDim.x;
    for (int e = i; e < E; e += stride) {
        int n = __builtin_nontemporal_load(idx + e);
        atomicAdd(&cntp[(size_t)((n >> 5) * NREP + rep) * 32], 1);
    }
}

// ---- pass 2: single-block scan over PADDED counters -> flat starts + padded cursors ----
__global__ __launch_bounds__(1024) void scan_pad(
    const int* __restrict__ cntp, int* __restrict__ sflat, int* __restrict__ cursp)
{
    __shared__ int wsum[16];
    __shared__ int running_s;
    int tid = threadIdx.x, lane = tid & 63, wv = tid >> 6;
    if (tid == 0) running_s = 0;
    __syncthreads();
    for (int base = 0; base < NFLAT; base += 4096) {
        int i0 = base + tid * 4;
        int c0 = 0, c1 = 0, c2 = 0, c3 = 0;
        if (i0     < NFLAT) c0 = cntp[(size_t)(i0    ) * 32];
        if (i0 + 1 < NFLAT) c1 = cntp[(size_t)(i0 + 1) * 32];
        if (i0 + 2 < NFLAT) c2 = cntp[(size_t)(i0 + 2) * 32];
        if (i0 + 3 < NFLAT) c3 = cntp[(size_t)(i0 + 3) * 32];
        int t = c0 + c1 + c2 + c3;
        int x = t;
        #pragma unroll
        for (int d = 1; d < 64; d <<= 1) {
            int v = __shfl_up(x, d);
            if (lane >= d) x += v;
        }
        if (lane == 63) wsum[wv] = x;
        __syncthreads();
        if (wv == 0 && lane < 16) {
            int y = wsum[lane];
            #pragma unroll
            for (int d = 1; d < 16; d <<= 1) {
                int v = __shfl_up(y, d);
                if (lane >= d) y += v;
            }
            wsum[lane] = y;
        }
        __syncthreads();
        int woff = (wv > 0) ? wsum[wv - 1] : 0;
        int r = running_s;
        int excl = r + woff + (x - t);
        int s0 = excl, s1 = excl + c0, s2 = s1 + c1, s3 = s2 + c2;
        if (i0     < NFLAT) { sflat[i0]     = s0; cursp[(size_t)(i0    ) * 32] = s0; }
        if (i0 + 1 < NFLAT) { sflat[i0 + 1] = s1; cursp[(size_t)(i0 + 1) * 32] = s1; }
        if (i0 + 2 < NFLAT) { sflat[i0 + 2] = s2; cursp[(size_t)(i0 + 2) * 32] = s2; }
        if (i0 + 3 < NFLAT) { sflat[i0 + 3] = s3; cursp[(size_t)(i0 + 3) * 32] = s3; }
        int total = wsum[15];
        __syncthreads();
        if (tid == 0) running_s = r + total;
    }
    __syncthreads();
    if (tid == 0) sflat[NFLAT] = running_s;
}

// ---- pass 3: scatter 8B records (w:f32 | nloc:5b | e:22b) into bucket-replica regions ----
__global__ __launch_bounds__(256) void scatter_ew(
    const int* __restrict__ idx, const float* __restrict__ wts,
    int* __restrict__ cursp, u64* __restrict__ recs, int E)
{
    const int rep = blockIdx.x & (NREP - 1);
    int i = blockIdx.x * blockDim.x + threadIdx.x;
    int stride = gridDim.x * blockDim.x;
    for (int e = i; e < E; e += stride) {
        int   n = __builtin_nontemporal_load(idx + e);
        float w = __builtin_nontemporal_load(wts + e);
        int slot = atomicAdd(&cursp[(size_t)((n >> 5) * NREP + rep) * 32], 1);
        u64 rec = ((u64)__float_as_uint(w) << 32)
                | (uint)e | ((uint)(n & 31) << 22);
        recs[slot] = rec;
    }
}

// ---- pass 4 (FUSED sort+gather, DIRECT cf reads): one block per bucket ----
// A: histogram+den from recs; B: 32-lane scan; C: re-read recs, rank, sorted LDS write;
// D: per-wave nodes: per-lane DIRECT random cf loads (32 rows/instr in flight),
//    premult+f16 convert, 2x MFMA, register relu-reduce, coalesced store.
// MFMA 32x32x16 f16 mappings (verified R5-R11):
//   A-frag: lane(ucol,h) supplies A[row=ucol][k=8h+j]
//   B-frag: lane supplies B[k=8h+j][n=ucol] (emb^T)
__global__ __launch_bounds__(256) void sort_gather(
    const float* __restrict__ emb, const f32x4* __restrict__ cf4,
    const int* __restrict__ sflat, const u64* __restrict__ recs,
    float* __restrict__ out, int* __restrict__ flag)
{
    __shared__ u64  lrecs[CAP];           // 16 KB sorted records
    __shared__ int  hist[NPB], lcur[NPB], lstart[NPB];
    __shared__ float lden[NPB];

    const int tid  = threadIdx.x;
    const int l    = tid & 63;
    const int wv   = tid >> 6;
    const int ucol = l & 31;
    const int h    = l >> 5;
    const int b    = blockIdx.x;

    const int rs = sflat[b * NREP];
    const int re = sflat[b * NREP + NREP];
    const int n  = re - rs;

    if (tid < NPB) { hist[tid] = 0; lden[tid] = 0.f; }
    __syncthreads();
    if (n > CAP) { if (tid == 0) *flag = 1; return; }

    // A: per-node histogram + den (coalesced rec reads; recs land in L2 for pass C)
    for (int i = tid; i < n; i += 256) {
        u64 r = recs[rs + i];
        int nl = (int)((r >> 22) & 31u);
        atomicAdd(&hist[nl], 1);
        atomicAdd(&lden[nl], __uint_as_float((uint)(r >> 32)));
    }
    __syncthreads();

    // B: 32-lane exclusive scan
    if (tid < NPB) {
        int c = hist[tid];
        int x = c;
        #pragma unroll
        for (int d = 1; d < NPB; d <<= 1) {
            int v = __shfl_up(x, d);
            if (tid >= d) x += v;
        }
        lstart[tid] = x - c;
        lcur[tid]   = x - c;
    }
    __syncthreads();

    // C: re-read (L2-hot), rank, sorted write into LDS
    for (int i = tid; i < n; i += 256) {
        u64 r = recs[rs + i];
        int d = atomicAdd(&lcur[(int)((r >> 22) & 31u)], 1);
        lrecs[d] = r;
    }
    __syncthreads();

    // D: each wave handles nodes wv, wv+4, ...
    f16x8 b0, b1;
    #pragma unroll
    for (int j = 0; j < 8; ++j) {
        b0[j] = (_Float16)emb[ucol * 16 + 8 * h + j];
        b1[j] = (_Float16)emb[(ucol + 32) * 16 + 8 * h + j];
    }
    f32x16 zacc;
    #pragma unroll
    for (int i = 0; i < 16; ++i) zacc[i] = 0.f;

    for (int nl = wv; nl < NPB; nl += 4) {
        int s   = lstart[nl];
        int cnt = hist[nl];
        float r0 = 0.f, r1 = 0.f;
        for (int ch = 0; ch < cnt; ch += 32) {
            bool valid = (ch + ucol) < cnt;
            u64 r = lrecs[valid ? (s + ch + ucol) : s];   // broadcast across h-pair
            float w = valid ? __uint_as_float((uint)(r >> 32)) : 0.f;
            int   e = (int)((uint)r & 0x3FFFFFu);
            // per-lane random 64B row read: 32 rows in flight per instruction
            f32x4 c0 = cf4[(size_t)e * 4 + 2 * h];
            f32x4 c1 = cf4[(size_t)e * 4 + 2 * h + 1];
            f16x8 a;
            a[0] = (_Float16)(c0.x * w); a[1] = (_Float16)(c0.y * w);
            a[2] = (_Float16)(c0.z * w); a[3] = (_Float16)(c0.w * w);
            a[4] = (_Float16)(c1.x * w); a[5] = (_Float16)(c1.y * w);
            a[6] = (_Float16)(c1.z * w); a[7] = (_Float16)(c1.w * w);
            f32x16 d0 = __builtin_amdgcn_mfma_f32_32x32x16_f16(a, b0, zacc, 0, 0, 0);
            f32x16 d1 = __builtin_amdgcn_mfma_f32_32x32x16_f16(a, b1, zacc, 0, 0, 0);
            float t0 = 0.f, t1 = 0.f;
            #pragma unroll
            for (int r2 = 0; r2 < 16; ++r2) {
                t0 += fmaxf(d0[r2], 0.f);
                t1 += fmaxf(d1[r2], 0.f);
            }
            r0 += t0; r1 += t1;
        }
        r0 += __shfl_xor(r0, 32);
        r1 += __shfl_xor(r1, 32);
        int node = b * NPB + nl;
        float d = lden[nl];
        out[(size_t)node * 64 + l] = (h ? r1 : r0) / d;   // coalesced 256B
    }
}

// ================= guarded fallbacks (no-op when flag==0 / null) =================

__global__ __launch_bounds__(256) void zero_fb(
    float* __restrict__ out, float* __restrict__ den, int nout,
    const int* __restrict__ flag)
{
    if (flag && !*flag) return;
    int i = blockIdx.x * blockDim.x + threadIdx.x;
    int stride = gridDim.x * blockDim.x;
    for (int j = i; j < nout; j += stride) out[j] = 0.f;
    for (int j = i; j < NODES; j += stride) den[j] = 0.f;
}

__global__ __launch_bounds__(256) void edge_scatter_fb(
    const float* __restrict__ emb, const float* __restrict__ cf,
    const float* __restrict__ wts, const int* __restrict__ idx,
    float* __restrict__ num, float* __restrict__ den, int E,
    const int* __restrict__ flag)
{
    if (flag && !*flag) return;
    const int lane = threadIdx.x & 63;
    float er[16];
    #pragma unroll
    for (int f = 0; f < 16; ++f) er[f] = emb[lane * 16 + f];
    int wid = rfl_i((int)((blockIdx.x * blockDim.x + threadIdx.x) >> 6));
    int nw = (gridDim.x * blockDim.x) >> 6;
    for (int e = wid; e < E; e += nw) {
        const float* c = cf + (size_t)e * 16;
        float a = 0.f;
        #pragma unroll
        for (int f = 0; f < 16; ++f) a = fmaf(c[f], er[f], a);
        float wv = wts[e];
        int n = idx[e];
        unsafeAtomicAdd(num + (size_t)n * 64 + lane, fmaxf(a, 0.f) * wv);
        if (lane == 0) unsafeAtomicAdd(den + n, wv);
    }
}

__global__ __launch_bounds__(256) void divide_fb(
    float* __restrict__ out, const float* __restrict__ den, int nvec,
    const int* __restrict__ flag)
{
    if (flag && !*flag) return;
    int i = blockIdx.x * blockDim.x + threadIdx.x;
    int stride = gridDim.x * blockDim.x;
    float4* o4 = reinterpret_cast<float4*>(out);
    for (; i < nvec; i += stride) {
        float4 v = o4[i];
        float d = den[i >> 4];
        v.x /= d; v.y /= d; v.z /= d; v.w /= d;
        o4[i] = v;
    }
}

extern "C" void kernel_launch(void* const* d_in, const int* in_sizes, int n_in,
                              void* d_out, int out_size, void* d_ws, size_t ws_size,
                              hipStream_t stream)
{
    const float* emb = (const float*)d_in[0];   // (64,16)
    const float* cf  = (const float*)d_in[1];   // (E,16)
    const float* wts = (const float*)d_in[2];   // (E,)
    const int*   idx = (const int*)d_in[3];     // (E,)
    int E = in_sizes[2];
    float* out = (float*)d_out;

    // ws layout (~33 MB)
    char* p = (char*)d_ws;
    auto take = [&](size_t bytes) { char* r = p; p += (bytes + 255) & ~(size_t)255; return r; };
    int*  cntp  = (int*)take((size_t)NFLAT * 32 * sizeof(int));   // 3.2 MB padded
    int*  cursp = (int*)take((size_t)NFLAT * 32 * sizeof(int));   // 3.2 MB padded
    int*  sflat = (int*)take((size_t)(NFLAT + 1) * sizeof(int));
    float* den  = (float*)take((size_t)NODES * sizeof(float));    // fallback only
    int*  flag  = (int*)take(256);
    u64*  recs  = (u64*)take((size_t)E * sizeof(u64));
    size_t need = (size_t)(p - (char*)d_ws);

    if (E < (1 << 22) && ws_size >= need) {
        (void)hipMemsetAsync(cntp, 0, (size_t)NFLAT * 32 * sizeof(int), stream);
        (void)hipMemsetAsync(flag, 0, sizeof(int), stream);
        count_pad<<<4096, 256, 0, stream>>>(idx, cntp, E);
        scan_pad<<<1, 1024, 0, stream>>>(cntp, sflat, cursp);
        scatter_ew<<<4096, 256, 0, stream>>>(idx, wts, cursp, recs, E);
        sort_gather<<<NBUCK, 256, 0, stream>>>(
            emb, (const f32x4*)cf, sflat, recs, out, flag);
        // guarded fallback chain (no-ops when flag==0)
        zero_fb<<<2048, 256, 0, stream>>>(out, den, out_size, flag);
        edge_scatter_fb<<<4096, 256, 0, stream>>>(emb, cf, wts, idx, out, den, E, flag);
        divide_fb<<<2048, 256, 0, stream>>>(out, den, out_size / 4, flag);
    } else {
        // host fallback: plain atomic scatter (needs only NODES floats of ws)
        float* den2 = (float*)d_ws;
        (void)hipMemsetAsync(d_out, 0, (size_t)out_size * sizeof(float), stream);
        (void)hipMemsetAsync(d_ws, 0, (size_t)NODES * sizeof(float), stream);
        edge_scatter_fb<<<4096, 256, 0, stream>>>(emb, cf, wts, idx, out, den2, E, nullptr);
        divide_fb<<<2048, 256, 0, stream>>>(out, den2, out_size / 4, nullptr);
    }
}

// Round 13
// 300.367 us; speedup vs baseline: 1.7479x; 1.4083x over previous
//
#include <hip/hip_runtime.h>
#include <cstddef>

constexpr int NODES = 100000;
constexpr int NPB   = 32;                      // nodes per bucket
constexpr int NBUCK = (NODES + NPB - 1) / NPB; // 3125 (×32 = exactly 100000)
constexpr int NREP  = 8;                       // region replicas (XCD-aligned)
constexpr int NFLAT = NBUCK * NREP;            // 25000
constexpr int RCAP  = 512;                     // fixed region capacity (mean 128, +34 sigma)
constexpr int CAP   = 2048;                    // per-bucket LDS capacity (mean 1024, +32 sigma)

typedef unsigned int uint;
typedef unsigned long long u64;
typedef __attribute__((ext_vector_type(8)))  _Float16 f16x8;
typedef __attribute__((ext_vector_type(16))) float    f32x16;
typedef __attribute__((ext_vector_type(4)))  float    f32x4;
typedef __attribute__((ext_vector_type(4)))  int      i32x4;

__device__ __forceinline__ int rfl_i(int x) {
    return __builtin_amdgcn_readfirstlane(x);
}

// ---- pass 1: scatter 8B records into FIXED-capacity bucket-replica regions ----
// No count/scan needed: region base = rid * RCAP, cursor doubles as fill count.
// rec = (w:f32 << 32) | (nloc:5b << 22) | (e:22b)
__global__ __launch_bounds__(256) void scatter_fix(
    const int* __restrict__ idx, const float* __restrict__ wts,
    int* __restrict__ cursp, u64* __restrict__ recs, int* __restrict__ flag, int E)
{
    const int rep = blockIdx.x & (NREP - 1);
    int i = blockIdx.x * blockDim.x + threadIdx.x;
    int stride = gridDim.x * blockDim.x;
    int e4 = E >> 2;
    const i32x4* idx4 = (const i32x4*)idx;
    const f32x4* wts4 = (const f32x4*)wts;
    for (int j = i; j < e4; j += stride) {
        i32x4 n4 = __builtin_nontemporal_load(idx4 + j);
        f32x4 w4 = __builtin_nontemporal_load(wts4 + j);
        int e = j << 2;
        #pragma unroll
        for (int k = 0; k < 4; ++k) {
            int   n = n4[k];
            float w = w4[k];
            int rid = (n >> 5) * NREP + rep;
            int pos = atomicAdd(&cursp[(size_t)rid * 32], 1);
            if (pos < RCAP) {
                u64 rec = ((u64)__float_as_uint(w) << 32)
                        | (uint)(e + k) | ((uint)(n & 31) << 22);
                recs[((size_t)rid << 9) + pos] = rec;
            } else {
                *flag = 1;
            }
        }
    }
    for (int e = (e4 << 2) + i; e < E; e += stride) {
        int   n = idx[e];
        float w = wts[e];
        int rid = (n >> 5) * NREP + rep;
        int pos = atomicAdd(&cursp[(size_t)rid * 32], 1);
        if (pos < RCAP) {
            u64 rec = ((u64)__float_as_uint(w) << 32)
                    | (uint)e | ((uint)(n & 31) << 22);
            recs[((size_t)rid << 9) + pos] = rec;
        } else {
            *flag = 1;
        }
    }
}

// ---- pass 2 (FUSED sort+gather, DIRECT cf reads): one block per bucket ----
// A: load recs from 8 fixed regions -> LDS raw + histogram + den
// B: 32-lane scan; C: rank from LDS raw -> LDS sorted
// D: per-wave nodes: per-lane DIRECT random cf loads, premult+f16, 2x MFMA,
//    register relu-reduce, coalesced 256B store.
// MFMA 32x32x16 f16 mappings (verified R5-R12):
//   A-frag: lane(ucol,h) supplies A[row=ucol][k=8h+j]
//   B-frag: lane supplies B[k=8h+j][n=ucol] (emb^T)
__global__ __launch_bounds__(256) void sort_gather(
    const float* __restrict__ emb, const f32x4* __restrict__ cf4,
    const int* __restrict__ cursp, const u64* __restrict__ recs,
    float* __restrict__ out, int* __restrict__ flag)
{
    __shared__ u64  lraw[CAP];            // 16 KB
    __shared__ u64  lsort[CAP];           // 16 KB
    __shared__ int  roff[NREP + 1];
    __shared__ int  hist[NPB], lcur[NPB], lstart[NPB];
    __shared__ float lden[NPB];

    const int tid  = threadIdx.x;
    const int l    = tid & 63;
    const int wv   = tid >> 6;
    const int ucol = l & 31;
    const int h    = l >> 5;
    const int b    = blockIdx.x;

    if (*flag) return;

    if (tid < NPB) { hist[tid] = 0; lden[tid] = 0.f; }
    if (tid == 0) {
        int t = 0;
        #pragma unroll
        for (int r = 0; r < NREP; ++r) {
            roff[r] = t;
            int f = cursp[(size_t)(b * NREP + r) * 32];
            t += (f < RCAP) ? f : RCAP;
        }
        roff[NREP] = t;
    }
    __syncthreads();
    const int n = roff[NREP];
    if (n > CAP) { if (tid == 0) *flag = 1; return; }

    // A: load from 8 regions into LDS raw + per-node histogram + den
    for (int r = 0; r < NREP; ++r) {
        int o = roff[r];
        int f = roff[r + 1] - o;
        size_t base = (size_t)(b * NREP + r) << 9;
        for (int i = tid; i < f; i += 256) {
            u64 rec = recs[base + i];
            lraw[o + i] = rec;
            int nl = (int)((rec >> 22) & 31u);
            atomicAdd(&hist[nl], 1);
            atomicAdd(&lden[nl], __uint_as_float((uint)(rec >> 32)));
        }
    }
    __syncthreads();

    // B: 32-lane exclusive scan
    if (tid < NPB) {
        int c = hist[tid];
        int x = c;
        #pragma unroll
        for (int d = 1; d < NPB; d <<= 1) {
            int v = __shfl_up(x, d);
            if (tid >= d) x += v;
        }
        lstart[tid] = x - c;
        lcur[tid]   = x - c;
    }
    __syncthreads();

    // C: rank + sorted write (LDS -> LDS)
    for (int i = tid; i < n; i += 256) {
        u64 rec = lraw[i];
        int d = atomicAdd(&lcur[(int)((rec >> 22) & 31u)], 1);
        lsort[d] = rec;
    }
    __syncthreads();

    // D: each wave handles nodes wv, wv+4, ...
    f16x8 b0, b1;
    #pragma unroll
    for (int j = 0; j < 8; ++j) {
        b0[j] = (_Float16)emb[ucol * 16 + 8 * h + j];
        b1[j] = (_Float16)emb[(ucol + 32) * 16 + 8 * h + j];
    }
    f32x16 zacc;
    #pragma unroll
    for (int i = 0; i < 16; ++i) zacc[i] = 0.f;

    for (int nl = wv; nl < NPB; nl += 4) {
        int s   = lstart[nl];
        int cnt = hist[nl];
        float r0 = 0.f, r1 = 0.f;
        for (int ch = 0; ch < cnt; ch += 32) {
            bool valid = (ch + ucol) < cnt;
            u64 rec = lsort[valid ? (s + ch + ucol) : s];
            float w = valid ? __uint_as_float((uint)(rec >> 32)) : 0.f;
            int   e = (int)((uint)rec & 0x3FFFFFu);
            // per-lane random 64B row read: 32 rows in flight per instruction
            f32x4 c0 = cf4[(size_t)e * 4 + 2 * h];
            f32x4 c1 = cf4[(size_t)e * 4 + 2 * h + 1];
            f16x8 a;
            a[0] = (_Float16)(c0.x * w); a[1] = (_Float16)(c0.y * w);
            a[2] = (_Float16)(c0.z * w); a[3] = (_Float16)(c0.w * w);
            a[4] = (_Float16)(c1.x * w); a[5] = (_Float16)(c1.y * w);
            a[6] = (_Float16)(c1.z * w); a[7] = (_Float16)(c1.w * w);
            f32x16 d0 = __builtin_amdgcn_mfma_f32_32x32x16_f16(a, b0, zacc, 0, 0, 0);
            f32x16 d1 = __builtin_amdgcn_mfma_f32_32x32x16_f16(a, b1, zacc, 0, 0, 0);
            float t0 = 0.f, t1 = 0.f;
            #pragma unroll
            for (int r2 = 0; r2 < 16; ++r2) {
                t0 += fmaxf(d0[r2], 0.f);
                t1 += fmaxf(d1[r2], 0.f);
            }
            r0 += t0; r1 += t1;
        }
        r0 += __shfl_xor(r0, 32);
        r1 += __shfl_xor(r1, 32);
        int node = b * NPB + nl;
        float d = lden[nl];
        out[(size_t)node * 64 + l] = (h ? r1 : r0) / d;   // coalesced 256B
    }
}

// ================= guarded fallbacks (no-op when flag==0 / null) =================

__global__ __launch_bounds__(256) void zero_fb(
    float* __restrict__ out, float* __restrict__ den, int nout,
    const int* __restrict__ flag)
{
    if (flag && !*flag) return;
    int i = blockIdx.x * blockDim.x + threadIdx.x;
    int stride = gridDim.x * blockDim.x;
    for (int j = i; j < nout; j += stride) out[j] = 0.f;
    for (int j = i; j < NODES; j += stride) den[j] = 0.f;
}

__global__ __launch_bounds__(256) void edge_scatter_fb(
    const float* __restrict__ emb, const float* __restrict__ cf,
    const float* __restrict__ wts, const int* __restrict__ idx,
    float* __restrict__ num, float* __restrict__ den, int E,
    const int* __restrict__ flag)
{
    if (flag && !*flag) return;
    const int lane = threadIdx.x & 63;
    float er[16];
    #pragma unroll
    for (int f = 0; f < 16; ++f) er[f] = emb[lane * 16 + f];
    int wid = rfl_i((int)((blockIdx.x * blockDim.x + threadIdx.x) >> 6));
    int nw = (gridDim.x * blockDim.x) >> 6;
    for (int e = wid; e < E; e += nw) {
        const float* c = cf + (size_t)e * 16;
        float a = 0.f;
        #pragma unroll
        for (int f = 0; f < 16; ++f) a = fmaf(c[f], er[f], a);
        float wv = wts[e];
        int n = idx[e];
        unsafeAtomicAdd(num + (size_t)n * 64 + lane, fmaxf(a, 0.f) * wv);
        if (lane == 0) unsafeAtomicAdd(den + n, wv);
    }
}

__global__ __launch_bounds__(256) void divide_fb(
    float* __restrict__ out, const float* __restrict__ den, int nvec,
    const int* __restrict__ flag)
{
    if (flag && !*flag) return;
    int i = blockIdx.x * blockDim.x + threadIdx.x;
    int stride = gridDim.x * blockDim.x;
    float4* o4 = reinterpret_cast<float4*>(out);
    for (; i < nvec; i += stride) {
        float4 v = o4[i];
        float d = den[i >> 4];
        v.x /= d; v.y /= d; v.z /= d; v.w /= d;
        o4[i] = v;
    }
}

extern "C" void kernel_launch(void* const* d_in, const int* in_sizes, int n_in,
                              void* d_out, int out_size, void* d_ws, size_t ws_size,
                              hipStream_t stream)
{
    const float* emb = (const float*)d_in[0];   // (64,16)
    const float* cf  = (const float*)d_in[1];   // (E,16)
    const float* wts = (const float*)d_in[2];   // (E,)
    const int*   idx = (const int*)d_in[3];     // (E,)
    int E = in_sizes[2];
    float* out = (float*)d_out;

    // ws layout (~106 MB)
    char* p = (char*)d_ws;
    auto take = [&](size_t bytes) { char* r = p; p += (bytes + 255) & ~(size_t)255; return r; };
    int*  cursp = (int*)take((size_t)NFLAT * 32 * sizeof(int));       // 3.2 MB padded
    float* den  = (float*)take((size_t)NODES * sizeof(float));        // fallback only
    int*  flag  = (int*)take(256);
    u64*  recs  = (u64*)take((size_t)NFLAT * RCAP * sizeof(u64));     // 102.4 MB fixed regions
    size_t need = (size_t)(p - (char*)d_ws);

    if (E < (1 << 22) && ws_size >= need) {
        (void)hipMemsetAsync(cursp, 0, (size_t)NFLAT * 32 * sizeof(int), stream);
        (void)hipMemsetAsync(flag, 0, sizeof(int), stream);
        scatter_fix<<<4096, 256, 0, stream>>>(idx, wts, cursp, recs, flag, E);
        sort_gather<<<NBUCK, 256, 0, stream>>>(
            emb, (const f32x4*)cf, cursp, recs, out, flag);
        // guarded fallback chain (no-ops when flag==0)
        zero_fb<<<2048, 256, 0, stream>>>(out, den, out_size, flag);
        edge_scatter_fb<<<4096, 256, 0, stream>>>(emb, cf, wts, idx, out, den, E, flag);
        divide_fb<<<2048, 256, 0, stream>>>(out, den, out_size / 4, flag);
    } else {
        // host fallback: plain atomic scatter (needs only NODES floats of ws)
        float* den2 = (float*)d_ws;
        (void)hipMemsetAsync(d_out, 0, (size_t)out_size * sizeof(float), stream);
        (void)hipMemsetAsync(d_ws, 0, (size_t)NODES * sizeof(float), stream);
        edge_scatter_fb<<<4096, 256, 0, stream>>>(emb, cf, wts, idx, out, den2, E, nullptr);
        divide_fb<<<2048, 256, 0, stream>>>(out, den2, out_size / 4, nullptr);
    }
}

// Round 14
// 294.781 us; speedup vs baseline: 1.7810x; 1.0189x over previous
//
#include <hip/hip_runtime.h>
#include <cstddef>

constexpr int NODES = 100000;
constexpr int NPB   = 32;                      // nodes per bucket
constexpr int NBUCK = (NODES + NPB - 1) / NPB; // 3125 (×32 = exactly 100000)
constexpr int NREP  = 8;                       // region replicas (one per XCD)
constexpr int NFLAT = NBUCK * NREP;            // 25000
constexpr int RCAP  = 512;                     // fixed region capacity
constexpr int CAP   = 2048;                    // per-bucket LDS capacity

typedef unsigned int uint;
typedef unsigned long long u64;
typedef __attribute__((ext_vector_type(8)))  _Float16 f16x8;
typedef __attribute__((ext_vector_type(16))) float    f32x16;
typedef __attribute__((ext_vector_type(4)))  float    f32x4;
typedef __attribute__((ext_vector_type(4)))  int      i32x4;

__device__ __forceinline__ int rfl_i(int x) {
    return __builtin_amdgcn_readfirstlane(x);
}
// hardware XCD id (gfx950; HW-verified readable per learn_hip m09)
__device__ __forceinline__ int xcd_id() {
    int x;
    asm volatile("s_getreg_b32 %0, hwreg(HW_REG_XCC_ID, 0, 4)" : "=s"(x));
    return x;
}

// ---- pass 1: scatter 8B records into FIXED-capacity bucket-replica regions ----
// rep = REAL XCD id -> each region's tail line is owned by exactly one L2.
// rec = (w:f32 << 32) | (nloc:5b << 22) | (e:22b)
__global__ __launch_bounds__(256) void scatter_fix(
    const int* __restrict__ idx, const float* __restrict__ wts,
    int* __restrict__ cursp, u64* __restrict__ recs, int* __restrict__ flag, int E)
{
    const int rep = xcd_id() & (NREP - 1);
    int i = blockIdx.x * blockDim.x + threadIdx.x;
    int stride = gridDim.x * blockDim.x;
    int e4 = E >> 2;
    const i32x4* idx4 = (const i32x4*)idx;
    const f32x4* wts4 = (const f32x4*)wts;
    for (int j = i; j < e4; j += stride) {
        i32x4 n4 = __builtin_nontemporal_load(idx4 + j);
        f32x4 w4 = __builtin_nontemporal_load(wts4 + j);
        int e = j << 2;
        #pragma unroll
        for (int k = 0; k < 4; ++k) {
            int   n = n4[k];
            float w = w4[k];
            int rid = (n >> 5) * NREP + rep;
            int pos = atomicAdd(&cursp[(size_t)rid * 32], 1);
            if (pos < RCAP) {
                u64 rec = ((u64)__float_as_uint(w) << 32)
                        | (uint)(e + k) | ((uint)(n & 31) << 22);
                recs[((size_t)rid << 9) + pos] = rec;
            } else {
                *flag = 1;
            }
        }
    }
    for (int e = (e4 << 2) + i; e < E; e += stride) {
        int   n = idx[e];
        float w = wts[e];
        int rid = (n >> 5) * NREP + rep;
        int pos = atomicAdd(&cursp[(size_t)rid * 32], 1);
        if (pos < RCAP) {
            u64 rec = ((u64)__float_as_uint(w) << 32)
                    | (uint)e | ((uint)(n & 31) << 22);
            recs[((size_t)rid << 9) + pos] = rec;
        } else {
            *flag = 1;
        }
    }
}

// ---- pass 2 (FUSED sort+gather, DIRECT cf reads): one block per bucket ----
// A: load recs from 8 fixed regions -> LDS raw + histogram + den
// B: 32-lane scan; C: rank from LDS raw -> LDS sorted
// D: per-wave nodes: per-lane DIRECT random cf loads, premult+f16, 2x MFMA,
//    register relu-reduce, coalesced 256B store.
// MFMA 32x32x16 f16 mappings (verified R5-R13):
//   A-frag: lane(ucol,h) supplies A[row=ucol][k=8h+j]
//   B-frag: lane supplies B[k=8h+j][n=ucol] (emb^T)
__global__ __launch_bounds__(256) void sort_gather(
    const float* __restrict__ emb, const f32x4* __restrict__ cf4,
    const int* __restrict__ cursp, const u64* __restrict__ recs,
    float* __restrict__ out, int* __restrict__ flag)
{
    __shared__ u64  lraw[CAP];            // 16 KB
    __shared__ u64  lsort[CAP];           // 16 KB
    __shared__ int  roff[NREP + 1];
    __shared__ int  hist[NPB], lcur[NPB], lstart[NPB];
    __shared__ float lden[NPB];

    const int tid  = threadIdx.x;
    const int l    = tid & 63;
    const int wv   = tid >> 6;
    const int ucol = l & 31;
    const int h    = l >> 5;
    const int b    = blockIdx.x;

    if (*flag) return;

    if (tid < NPB) { hist[tid] = 0; lden[tid] = 0.f; }
    if (tid == 0) {
        int t = 0;
        #pragma unroll
        for (int r = 0; r < NREP; ++r) {
            roff[r] = t;
            int f = cursp[(size_t)(b * NREP + r) * 32];
            t += (f < RCAP) ? f : RCAP;
        }
        roff[NREP] = t;
    }
    __syncthreads();
    const int n = roff[NREP];
    if (n > CAP) { if (tid == 0) *flag = 1; return; }

    // A: load from 8 regions into LDS raw + per-node histogram + den
    for (int r = 0; r < NREP; ++r) {
        int o = roff[r];
        int f = roff[r + 1] - o;
        size_t base = (size_t)(b * NREP + r) << 9;
        for (int i = tid; i < f; i += 256) {
            u64 rec = recs[base + i];
            lraw[o + i] = rec;
            int nl = (int)((rec >> 22) & 31u);
            atomicAdd(&hist[nl], 1);
            atomicAdd(&lden[nl], __uint_as_float((uint)(rec >> 32)));
        }
    }
    __syncthreads();

    // B: 32-lane exclusive scan
    if (tid < NPB) {
        int c = hist[tid];
        int x = c;
        #pragma unroll
        for (int d = 1; d < NPB; d <<= 1) {
            int v = __shfl_up(x, d);
            if (tid >= d) x += v;
        }
        lstart[tid] = x - c;
        lcur[tid]   = x - c;
    }
    __syncthreads();

    // C: rank + sorted write (LDS -> LDS)
    for (int i = tid; i < n; i += 256) {
        u64 rec = lraw[i];
        int d = atomicAdd(&lcur[(int)((rec >> 22) & 31u)], 1);
        lsort[d] = rec;
    }
    __syncthreads();

    // D: each wave handles nodes wv, wv+4, ...
    f16x8 b0, b1;
    #pragma unroll
    for (int j = 0; j < 8; ++j) {
        b0[j] = (_Float16)emb[ucol * 16 + 8 * h + j];
        b1[j] = (_Float16)emb[(ucol + 32) * 16 + 8 * h + j];
    }
    f32x16 zacc;
    #pragma unroll
    for (int i = 0; i < 16; ++i) zacc[i] = 0.f;

    for (int nl = wv; nl < NPB; nl += 4) {
        int s   = lstart[nl];
        int cnt = hist[nl];
        float r0 = 0.f, r1 = 0.f;
        for (int ch = 0; ch < cnt; ch += 32) {
            bool valid = (ch + ucol) < cnt;
            u64 rec = lsort[valid ? (s + ch + ucol) : s];
            float w = valid ? __uint_as_float((uint)(rec >> 32)) : 0.f;
            int   e = (int)((uint)rec & 0x3FFFFFu);
            // per-lane random 64B row read: 32 rows in flight per instruction
            f32x4 c0 = cf4[(size_t)e * 4 + 2 * h];
            f32x4 c1 = cf4[(size_t)e * 4 + 2 * h + 1];
            f16x8 a;
            a[0] = (_Float16)(c0.x * w); a[1] = (_Float16)(c0.y * w);
            a[2] = (_Float16)(c0.z * w); a[3] = (_Float16)(c0.w * w);
            a[4] = (_Float16)(c1.x * w); a[5] = (_Float16)(c1.y * w);
            a[6] = (_Float16)(c1.z * w); a[7] = (_Float16)(c1.w * w);
            f32x16 d0 = __builtin_amdgcn_mfma_f32_32x32x16_f16(a, b0, zacc, 0, 0, 0);
            f32x16 d1 = __builtin_amdgcn_mfma_f32_32x32x16_f16(a, b1, zacc, 0, 0, 0);
            float t0 = 0.f, t1 = 0.f;
            #pragma unroll
            for (int r2 = 0; r2 < 16; ++r2) {
                t0 += fmaxf(d0[r2], 0.f);
                t1 += fmaxf(d1[r2], 0.f);
            }
            r0 += t0; r1 += t1;
        }
        r0 += __shfl_xor(r0, 32);
        r1 += __shfl_xor(r1, 32);
        int node = b * NPB + nl;
        float d = lden[nl];
        out[(size_t)node * 64 + l] = (h ? r1 : r0) / d;   // coalesced 256B
    }
}

// ================= guarded fallbacks (no-op when flag==0 / null) =================

__global__ __launch_bounds__(256) void zero_fb(
    float* __restrict__ out, float* __restrict__ den, int nout,
    const int* __restrict__ flag)
{
    if (flag && !*flag) return;
    int i = blockIdx.x * blockDim.x + threadIdx.x;
    int stride = gridDim.x * blockDim.x;
    for (int j = i; j < nout; j += stride) out[j] = 0.f;
    for (int j = i; j < NODES; j += stride) den[j] = 0.f;
}

__global__ __launch_bounds__(256) void edge_scatter_fb(
    const float* __restrict__ emb, const float* __restrict__ cf,
    const float* __restrict__ wts, const int* __restrict__ idx,
    float* __restrict__ num, float* __restrict__ den, int E,
    const int* __restrict__ flag)
{
    if (flag && !*flag) return;
    const int lane = threadIdx.x & 63;
    float er[16];
    #pragma unroll
    for (int f = 0; f < 16; ++f) er[f] = emb[lane * 16 + f];
    int wid = rfl_i((int)((blockIdx.x * blockDim.x + threadIdx.x) >> 6));
    int nw = (gridDim.x * blockDim.x) >> 6;
    for (int e = wid; e < E; e += nw) {
        const float* c = cf + (size_t)e * 16;
        float a = 0.f;
        #pragma unroll
        for (int f = 0; f < 16; ++f) a = fmaf(c[f], er[f], a);
        float wv = wts[e];
        int n = idx[e];
        unsafeAtomicAdd(num + (size_t)n * 64 + lane, fmaxf(a, 0.f) * wv);
        if (lane == 0) unsafeAtomicAdd(den + n, wv);
    }
}

__global__ __launch_bounds__(256) void divide_fb(
    float* __restrict__ out, const float* __restrict__ den, int nvec,
    const int* __restrict__ flag)
{
    if (flag && !*flag) return;
    int i = blockIdx.x * blockDim.x + threadIdx.x;
    int stride = gridDim.x * blockDim.x;
    float4* o4 = reinterpret_cast<float4*>(out);
    for (; i < nvec; i += stride) {
        float4 v = o4[i];
        float d = den[i >> 4];
        v.x /= d; v.y /= d; v.z /= d; v.w /= d;
        o4[i] = v;
    }
}

extern "C" void kernel_launch(void* const* d_in, const int* in_sizes, int n_in,
                              void* d_out, int out_size, void* d_ws, size_t ws_size,
                              hipStream_t stream)
{
    const float* emb = (const float*)d_in[0];   // (64,16)
    const float* cf  = (const float*)d_in[1];   // (E,16)
    const float* wts = (const float*)d_in[2];   // (E,)
    const int*   idx = (const int*)d_in[3];     // (E,)
    int E = in_sizes[2];
    float* out = (float*)d_out;

    // ws layout (~106 MB)
    char* p = (char*)d_ws;
    auto take = [&](size_t bytes) { char* r = p; p += (bytes + 255) & ~(size_t)255; return r; };
    int*  cursp = (int*)take((size_t)NFLAT * 32 * sizeof(int));       // 3.2 MB padded
    float* den  = (float*)take((size_t)NODES * sizeof(float));        // fallback only
    int*  flag  = (int*)take(256);
    u64*  recs  = (u64*)take((size_t)NFLAT * RCAP * sizeof(u64));     // 102.4 MB fixed regions
    size_t need = (size_t)(p - (char*)d_ws);

    if (E < (1 << 22) && ws_size >= need) {
        (void)hipMemsetAsync(cursp, 0, (size_t)NFLAT * 32 * sizeof(int), stream);
        (void)hipMemsetAsync(flag, 0, sizeof(int), stream);
        scatter_fix<<<4096, 256, 0, stream>>>(idx, wts, cursp, recs, flag, E);
        sort_gather<<<NBUCK, 256, 0, stream>>>(
            emb, (const f32x4*)cf, cursp, recs, out, flag);
        // guarded fallback chain (no-ops when flag==0)
        zero_fb<<<2048, 256, 0, stream>>>(out, den, out_size, flag);
        edge_scatter_fb<<<4096, 256, 0, stream>>>(emb, cf, wts, idx, out, den, E, flag);
        divide_fb<<<2048, 256, 0, stream>>>(out, den, out_size / 4, flag);
    } else {
        // host fallback: plain atomic scatter (needs only NODES floats of ws)
        float* den2 = (float*)d_ws;
        (void)hipMemsetAsync(d_out, 0, (size_t)out_size * sizeof(float), stream);
        (void)hipMemsetAsync(d_ws, 0, (size_t)NODES * sizeof(float), stream);
        edge_scatter_fb<<<4096, 256, 0, stream>>>(emb, cf, wts, idx, out, den2, E, nullptr);
        divide_fb<<<2048, 256, 0, stream>>>(out, den2, out_size / 4, nullptr);
    }
}

// Round 15
// 238.121 us; speedup vs baseline: 2.2048x; 1.2379x over previous
//
#include <hip/hip_runtime.h>
#include <cstddef>

constexpr int NODES = 100000;
constexpr int NPB   = 128;                     // nodes per bucket
constexpr int NBUCK = (NODES + NPB - 1) / NPB; // 782
constexpr int RCAP  = 6400;                    // region capacity (recs); mean fill ~5000
constexpr int SLOTS = 12;                      // LDS bin slots in scatter
constexpr int SGRID = 256;                     // scatter blocks (persistent, 1/CU)

typedef unsigned int uint;
typedef unsigned long long u64;
typedef __attribute__((ext_vector_type(8)))  _Float16 f16x8;
typedef __attribute__((ext_vector_type(16))) float    f32x16;
typedef __attribute__((ext_vector_type(4)))  float    f32x4;
typedef __attribute__((ext_vector_type(4)))  uint     u32x4;
typedef __attribute__((ext_vector_type(2)))  int      i32x2;
typedef __attribute__((ext_vector_type(2)))  float    f32x2;

__device__ __forceinline__ int rfl_i(int x) {
    return __builtin_amdgcn_readfirstlane(x);
}

// rec = (w:f32 << 32) | (nloc:7b << 22) | (e:22b). w=0 recs are harmless padding.

// ---- pass 1: LDS-binned scatter; ALL bulk stores are full 64B lines ----
__global__ __launch_bounds__(256) void scatter_bin(
    const int* __restrict__ idx, const float* __restrict__ wts,
    int* __restrict__ gcur, u64* __restrict__ recs, int* __restrict__ flag, int E)
{
    __shared__ u64 slot[NBUCK][SLOTS];   // 75 KB
    __shared__ int cnt[NBUCK];

    const int tid = threadIdx.x;
    for (int b2 = tid; b2 < NBUCK; b2 += 256) cnt[b2] = 0;
    __syncthreads();

    const int chunk = (((E + SGRID - 1) / SGRID) + 511) & ~511;
    const int e0 = blockIdx.x * chunk;
    const int e1 = min(e0 + chunk, E);

#define INS(nn, ww, ee) do {                                                   \
    int bin_ = (nn) >> 7;                                                      \
    u64 rec_ = ((u64)__float_as_uint(ww) << 32)                                \
             | (uint)(ee) | ((uint)((nn) & 127) << 22);                        \
    int pos_ = atomicAdd(&cnt[bin_], 1);                                       \
    if (pos_ < SLOTS) slot[bin_][pos_] = rec_;                                 \
    else { int gp_ = atomicAdd(&gcur[(size_t)bin_ * 32], 1);                   \
           if (gp_ < RCAP) recs[(size_t)bin_ * RCAP + gp_] = rec_;             \
           else *flag = 1; }                                                   \
} while (0)

    for (int base = e0; base < e1; base += 512) {
        // insert: 2 edges/thread, coalesced 8B loads
        int e = base + tid * 2;
        if (e + 1 < e1) {
            i32x2 n2 = __builtin_nontemporal_load((const i32x2*)(idx + e));
            f32x2 w2 = __builtin_nontemporal_load((const f32x2*)(wts + e));
            INS(n2.x, w2.x, e);
            INS(n2.y, w2.y, e + 1);
        } else if (e < e1) {
            int   n1 = idx[e];
            float w1 = wts[e];
            INS(n1, w1, e);
        }
        __syncthreads();
        // flush: owner thread per bin; one full 64B line when >=8 recs
        for (int b2 = tid; b2 < NBUCK; b2 += 256) {
            int c = cnt[b2]; if (c > SLOTS) c = SLOTS;
            if (c >= 8) {
                int gp = atomicAdd(&gcur[(size_t)b2 * 32], 8);
                if (gp + 8 <= RCAP) {
                    u32x4* dst = (u32x4*)(recs + (size_t)b2 * RCAP + gp);
                    #pragma unroll
                    for (int i = 0; i < 4; ++i) dst[i] = *(u32x4*)&slot[b2][2 * i];
                } else *flag = 1;
                int rem = c - 8;
                #pragma unroll
                for (int i = 0; i < 4; ++i) if (i < rem) slot[b2][i] = slot[b2][8 + i];
                cnt[b2] = rem;
            }
        }
        __syncthreads();
    }
#undef INS

    // final flush: pad partial lines to 8 with w=0 sentinel recs -> full 64B stores
    for (int b2 = tid; b2 < NBUCK; b2 += 256) {
        int c = cnt[b2];               // <= 7 here
        if (c > 0) {
            int gp = atomicAdd(&gcur[(size_t)b2 * 32], 8);
            if (gp + 8 <= RCAP) {
                #pragma unroll
                for (int i = 0; i < 8; ++i)
                    if (i >= c) slot[b2][i] = (u64)((uint)((gp + i) & 127) << 22);
                u32x4* dst = (u32x4*)(recs + (size_t)b2 * RCAP + gp);
                #pragma unroll
                for (int i = 0; i < 4; ++i) dst[i] = *(u32x4*)&slot[b2][2 * i];
            } else *flag = 1;
        }
    }
}

// ---- pass 2 (FUSED sort+gather): one block per 128-node bucket ----
// A: stream recs -> hist + den; B: wave-0 scan (2 bins/lane); C: re-read, rank -> lsort;
// D: per-wave nodes: per-lane DIRECT random cf loads, premult+f16, 2x MFMA,
//    register relu-reduce, coalesced 256B store.
// MFMA 32x32x16 f16 mappings (verified R5-R14):
//   A-frag: lane(ucol,h) supplies A[row=ucol][k=8h+j]
//   B-frag: lane supplies B[k=8h+j][n=ucol] (emb^T)
__global__ __launch_bounds__(256) void sort_gather(
    const float* __restrict__ emb, const f32x4* __restrict__ cf4,
    const int* __restrict__ gcur, const u64* __restrict__ recs,
    float* __restrict__ out, int* __restrict__ flag)
{
    __shared__ u64  lsort[RCAP];          // 50 KB
    __shared__ int  hist[NPB], lcur_[NPB], lstart[NPB];
    __shared__ float lden[NPB];

    const int tid  = threadIdx.x;
    const int l    = tid & 63;
    const int wv   = tid >> 6;
    const int ucol = l & 31;
    const int h    = l >> 5;
    const int b    = blockIdx.x;

    if (*flag) return;

    if (tid < NPB) { hist[tid] = 0; lden[tid] = 0.f; }
    __syncthreads();

    int n = gcur[(size_t)b * 32];
    if (n > RCAP) n = RCAP;
    const u64* rbase = recs + (size_t)b * RCAP;

    // A: histogram + den (streaming; w=0 pads contribute nothing)
    for (int i = tid; i < n; i += 256) {
        u64 r = rbase[i];
        int nl = (int)((r >> 22) & 127u);
        atomicAdd(&hist[nl], 1);
        atomicAdd(&lden[nl], __uint_as_float((uint)(r >> 32)));
    }
    __syncthreads();

    // B: exclusive scan over 128 bins, wave 0, 2 bins per lane
    if (tid < 64) {
        int c0 = hist[2 * tid], c1 = hist[2 * tid + 1];
        int t = c0 + c1, x = t;
        #pragma unroll
        for (int d = 1; d < 64; d <<= 1) {
            int v = __shfl_up(x, d);
            if (tid >= d) x += v;
        }
        int excl = x - t;
        lstart[2 * tid]     = excl;      lstart[2 * tid + 1] = excl + c0;
        lcur_[2 * tid]      = excl;      lcur_[2 * tid + 1]  = excl + c0;
    }
    __syncthreads();

    // C: re-read (L2-hot), rank, sorted write into LDS
    for (int i = tid; i < n; i += 256) {
        u64 r = rbase[i];
        int d = atomicAdd(&lcur_[(int)((r >> 22) & 127u)], 1);
        lsort[d] = r;
    }
    __syncthreads();

    // D: each wave handles nodes wv, wv+4, ...
    f16x8 b0, b1;
    #pragma unroll
    for (int j = 0; j < 8; ++j) {
        b0[j] = (_Float16)emb[ucol * 16 + 8 * h + j];
        b1[j] = (_Float16)emb[(ucol + 32) * 16 + 8 * h + j];
    }
    f32x16 zacc;
    #pragma unroll
    for (int i = 0; i < 16; ++i) zacc[i] = 0.f;

    for (int nl = wv; nl < NPB; nl += 4) {
        int node = b * NPB + nl;
        if (node >= NODES) continue;
        int s   = lstart[nl];
        int cnt = hist[nl];
        float r0 = 0.f, r1 = 0.f;
        for (int ch = 0; ch < cnt; ch += 32) {
            bool valid = (ch + ucol) < cnt;
            u64 rec = lsort[valid ? (s + ch + ucol) : s];
            float w = valid ? __uint_as_float((uint)(rec >> 32)) : 0.f;
            int   e = (int)((uint)rec & 0x3FFFFFu);
            // per-lane random 64B row read: 32 rows in flight per instruction
            f32x4 c0 = cf4[(size_t)e * 4 + 2 * h];
            f32x4 c1 = cf4[(size_t)e * 4 + 2 * h + 1];
            f16x8 a;
            a[0] = (_Float16)(c0.x * w); a[1] = (_Float16)(c0.y * w);
            a[2] = (_Float16)(c0.z * w); a[3] = (_Float16)(c0.w * w);
            a[4] = (_Float16)(c1.x * w); a[5] = (_Float16)(c1.y * w);
            a[6] = (_Float16)(c1.z * w); a[7] = (_Float16)(c1.w * w);
            f32x16 d0 = __builtin_amdgcn_mfma_f32_32x32x16_f16(a, b0, zacc, 0, 0, 0);
            f32x16 d1 = __builtin_amdgcn_mfma_f32_32x32x16_f16(a, b1, zacc, 0, 0, 0);
            float t0 = 0.f, t1 = 0.f;
            #pragma unroll
            for (int r2 = 0; r2 < 16; ++r2) {
                t0 += fmaxf(d0[r2], 0.f);
                t1 += fmaxf(d1[r2], 0.f);
            }
            r0 += t0; r1 += t1;
        }
        r0 += __shfl_xor(r0, 32);
        r1 += __shfl_xor(r1, 32);
        float d = lden[nl];
        out[(size_t)node * 64 + l] = (h ? r1 : r0) / d;   // coalesced 256B
    }
}

// ================= guarded fallbacks (no-op when flag==0 / null) =================

__global__ __launch_bounds__(256) void zero_fb(
    float* __restrict__ out, float* __restrict__ den, int nout,
    const int* __restrict__ flag)
{
    if (flag && !*flag) return;
    int i = blockIdx.x * blockDim.x + threadIdx.x;
    int stride = gridDim.x * blockDim.x;
    for (int j = i; j < nout; j += stride) out[j] = 0.f;
    for (int j = i; j < NODES; j += stride) den[j] = 0.f;
}

__global__ __launch_bounds__(256) void edge_scatter_fb(
    const float* __restrict__ emb, const float* __restrict__ cf,
    const float* __restrict__ wts, const int* __restrict__ idx,
    float* __restrict__ num, float* __restrict__ den, int E,
    const int* __restrict__ flag)
{
    if (flag && !*flag) return;
    const int lane = threadIdx.x & 63;
    float er[16];
    #pragma unroll
    for (int f = 0; f < 16; ++f) er[f] = emb[lane * 16 + f];
    int wid = rfl_i((int)((blockIdx.x * blockDim.x + threadIdx.x) >> 6));
    int nw = (gridDim.x * blockDim.x) >> 6;
    for (int e = wid; e < E; e += nw) {
        const float* c = cf + (size_t)e * 16;
        float a = 0.f;
        #pragma unroll
        for (int f = 0; f < 16; ++f) a = fmaf(c[f], er[f], a);
        float wv = wts[e];
        int n = idx[e];
        unsafeAtomicAdd(num + (size_t)n * 64 + lane, fmaxf(a, 0.f) * wv);
        if (lane == 0) unsafeAtomicAdd(den + n, wv);
    }
}

__global__ __launch_bounds__(256) void divide_fb(
    float* __restrict__ out, const float* __restrict__ den, int nvec,
    const int* __restrict__ flag)
{
    if (flag && !*flag) return;
    int i = blockIdx.x * blockDim.x + threadIdx.x;
    int stride = gridDim.x * blockDim.x;
    float4* o4 = reinterpret_cast<float4*>(out);
    for (; i < nvec; i += stride) {
        float4 v = o4[i];
        float d = den[i >> 4];
        v.x /= d; v.y /= d; v.z /= d; v.w /= d;
        o4[i] = v;
    }
}

extern "C" void kernel_launch(void* const* d_in, const int* in_sizes, int n_in,
                              void* d_out, int out_size, void* d_ws, size_t ws_size,
                              hipStream_t stream)
{
    const float* emb = (const float*)d_in[0];   // (64,16)
    const float* cf  = (const float*)d_in[1];   // (E,16)
    const float* wts = (const float*)d_in[2];   // (E,)
    const int*   idx = (const int*)d_in[3];     // (E,)
    int E = in_sizes[2];
    float* out = (float*)d_out;

    // ws layout (~41 MB)
    char* p = (char*)d_ws;
    auto take = [&](size_t bytes) { char* r = p; p += (bytes + 255) & ~(size_t)255; return r; };
    int*  gcur = (int*)take((size_t)NBUCK * 32 * sizeof(int));    // 100 KB padded
    float* den = (float*)take((size_t)NODES * sizeof(float));     // fallback only
    int*  flag = (int*)take(256);
    u64*  recs = (u64*)take((size_t)NBUCK * RCAP * sizeof(u64));  // 40 MB fixed regions
    size_t need = (size_t)(p - (char*)d_ws);

    if (E < (1 << 22) && ws_size >= need) {
        (void)hipMemsetAsync(gcur, 0, (size_t)NBUCK * 32 * sizeof(int), stream);
        (void)hipMemsetAsync(flag, 0, sizeof(int), stream);
        scatter_bin<<<SGRID, 256, 0, stream>>>(idx, wts, gcur, recs, flag, E);
        sort_gather<<<NBUCK, 256, 0, stream>>>(
            emb, (const f32x4*)cf, gcur, recs, out, flag);
        // guarded fallback chain (no-ops when flag==0)
        zero_fb<<<2048, 256, 0, stream>>>(out, den, out_size, flag);
        edge_scatter_fb<<<4096, 256, 0, stream>>>(emb, cf, wts, idx, out, den, E, flag);
        divide_fb<<<2048, 256, 0, stream>>>(out, den, out_size / 4, flag);
    } else {
        // host fallback: plain atomic scatter (needs only NODES floats of ws)
        float* den2 = (float*)d_ws;
        (void)hipMemsetAsync(d_out, 0, (size_t)out_size * sizeof(float), stream);
        (void)hipMemsetAsync(d_ws, 0, (size_t)NODES * sizeof(float), stream);
        edge_scatter_fb<<<4096, 256, 0, stream>>>(emb, cf, wts, idx, out, den2, E, nullptr);
        divide_fb<<<2048, 256, 0, stream>>>(out, den2, out_size / 4, nullptr);
    }
}